// Round 10
// baseline (791.135 us; speedup 1.0000x reference)
//
#include <hip/hip_runtime.h>
#include <hip/hip_bf16.h>
#include <math.h>

// Problem constants (fixed by the reference)
#define N_NODES   100000
#define N_PAD     100096   // multiple of 128 (782 row-tiles), safe OOB rows
#define NT_TILES  782      // N_PAD / 128
#define N_EDGES   1000000
#define D_IN      64
#define T_ET      4
#define H_DIM     256
#define TD        256      // T_ET * D_IN
#define NSEG      400000   // N_NODES * T_ET

typedef __attribute__((ext_vector_type(8))) short short8;   // 8 bf16 (4 VGPRs)
typedef __attribute__((ext_vector_type(4))) float floatx4;  // MFMA C/D

__device__ __forceinline__ unsigned short f2b(float f) {
    __hip_bfloat16 h = __float2bfloat16(f);
    return *reinterpret_cast<unsigned short*>(&h);
}
__device__ __forceinline__ unsigned pack2(float a, float b) {
    return (unsigned)f2b(a) | ((unsigned)f2b(b) << 16);
}

// global->LDS DMA: 16 B per lane, LDS dst = wave-uniform base + lane*16
#define GLOAD16(gsrc, ldst)                                                  \
    __builtin_amdgcn_global_load_lds(                                        \
        (const __attribute__((address_space(1))) unsigned int*)(gsrc),       \
        (__attribute__((address_space(3))) unsigned int*)(ldst), 16, 0, 0)

// ---------------------------------------------------------------------------
// CSR build (unchanged): histogram -> scan -> place
// ---------------------------------------------------------------------------
__global__ __launch_bounds__(256) void hist_kernel(
    const int* __restrict__ edge_index, const int* __restrict__ edge_type,
    int* __restrict__ counts)
{
    int e = blockIdx.x * 256 + threadIdx.x;
    if (e >= N_EDGES) return;
    int dst = edge_index[N_EDGES + e];
    int ty  = edge_type[e];
    atomicAdd(&counts[dst * T_ET + ty], 1);
}

__global__ __launch_bounds__(256) void scan1_kernel(
    const int* __restrict__ counts, int* __restrict__ offsets,
    int* __restrict__ partials)
{
    __shared__ int tsum[256];
    const int tid = threadIdx.x;
    const int base = blockIdx.x * 1024 + tid * 4;
    int v[4]; int s = 0;
    #pragma unroll
    for (int i = 0; i < 4; ++i) {
        v[i] = (base + i < NSEG) ? counts[base + i] : 0;
        s += v[i];
    }
    tsum[tid] = s;
    __syncthreads();
    #pragma unroll
    for (int off = 1; off < 256; off <<= 1) {
        int t = (tid >= off) ? tsum[tid - off] : 0;
        __syncthreads();
        tsum[tid] += t;
        __syncthreads();
    }
    int run = tsum[tid] - s;
    #pragma unroll
    for (int i = 0; i < 4; ++i) {
        if (base + i < NSEG) offsets[base + i] = run;
        run += v[i];
    }
    if (tid == 255) partials[blockIdx.x] = tsum[255];
}

__global__ __launch_bounds__(512) void scan2_kernel(int* __restrict__ partials, int nb)
{
    __shared__ int sh[512];
    const int tid = threadIdx.x;
    int v = (tid < nb) ? partials[tid] : 0;
    sh[tid] = v;
    __syncthreads();
    #pragma unroll
    for (int off = 1; off < 512; off <<= 1) {
        int t = (tid >= off) ? sh[tid - off] : 0;
        __syncthreads();
        sh[tid] += t;
        __syncthreads();
    }
    if (tid < nb) partials[tid] = sh[tid] - v;
}

__global__ __launch_bounds__(256) void scan3_kernel(
    int* __restrict__ offsets, const int* __restrict__ partials,
    int* __restrict__ cursor)
{
    int i = blockIdx.x * 256 + threadIdx.x;
    if (i < NSEG) {
        int o = offsets[i] + partials[i >> 10];
        offsets[i] = o;
        cursor[i]  = o;
    }
    if (i == 0) offsets[NSEG] = N_EDGES;
}

__global__ __launch_bounds__(256) void place_kernel(
    const int* __restrict__ edge_index, const int* __restrict__ edge_type,
    const float* __restrict__ edge_w, int* __restrict__ cursor,
    int2* __restrict__ recs)
{
    int e = blockIdx.x * 256 + threadIdx.x;
    if (e >= N_EDGES) return;
    int src = edge_index[e];
    int dst = edge_index[N_EDGES + e];
    int ty  = edge_type[e];
    int seg = dst * T_ET + ty;
    int pos = atomicAdd(&cursor[seg], 1);
    recs[pos] = make_int2(src, __float_as_int(edge_w[e]));
}

// gather: 16 threads per segment; reads bf16 xb, accumulates f32, writes bf16
__global__ __launch_bounds__(256) void gather_kernel(
    const unsigned short* __restrict__ xb, const int* __restrict__ offsets,
    const int2* __restrict__ recs, unsigned* __restrict__ updb_u32)
{
    int gid = blockIdx.x * 256 + threadIdx.x;
    int seg = gid >> 4;
    int t   = gid & 15;
    if (seg >= NSEG) return;
    int start = offsets[seg];
    int end   = offsets[seg + 1];
    float a0 = 0.f, a1 = 0.f, a2 = 0.f, a3 = 0.f;
    for (int p = start; p < end; ++p) {
        int2 r = recs[p];
        float w = __int_as_float(r.y);
        uint2 xv = reinterpret_cast<const uint2*>(xb)[r.x * 16 + t];
        a0 += w * __uint_as_float(xv.x << 16);
        a1 += w * __uint_as_float(xv.x & 0xffff0000u);
        a2 += w * __uint_as_float(xv.y << 16);
        a3 += w * __uint_as_float(xv.y & 0xffff0000u);
    }
    uint2 o;
    o.x = pack2(a0, a1);
    o.y = pack2(a2, a3);
    reinterpret_cast<uint2*>(updb_u32)[seg * 16 + t] = o;
}

// ---------------------------------------------------------------------------
// prep: f32 -> bf16. w_ih permuted with the hidden physical layout:
//   phys p holds logical col c(p) = (p&15)*16 + (p>>4)
// ---------------------------------------------------------------------------
__global__ __launch_bounds__(256) void conv_x_kernel(
    const float* __restrict__ x, unsigned short* __restrict__ xb)
{
    int i = blockIdx.x * 256 + threadIdx.x;
    if (i >= N_PAD * 16) return;
    int row = i >> 4;
    int srow = row < N_NODES ? row : N_NODES - 1;
    float4 v = reinterpret_cast<const float4*>(x)[srow * 16 + (i & 15)];
    uint2 o;
    o.x = pack2(v.x, v.y);
    o.y = pack2(v.z, v.w);
    reinterpret_cast<uint2*>(xb)[i] = o;
}

__global__ __launch_bounds__(256) void conv_w_kernel(
    const float* __restrict__ w1, const float* __restrict__ wih,
    const float* __restrict__ whh,
    unsigned short* __restrict__ w1b, unsigned short* __restrict__ wihp,
    unsigned short* __restrict__ whhb)
{
    int i = blockIdx.x * 256 + threadIdx.x;
    if (i < 65536) { w1b[i] = f2b(w1[i]); return; }
    i -= 65536;
    if (i < 49152) {
        int n = i >> 8, p = i & 255;
        int k = (p & 15) * 16 + (p >> 4);
        wihp[i] = f2b(wih[n * 256 + k]);
        return;
    }
    i -= 49152;
    if (i < 12288) whhb[i] = f2b(whh[i]);
}

// ---------------------------------------------------------------------------
// Kernel A: hidden = relu(upd @ W1^T + b1), W1-stationary in LDS (128 KB).
// 512 threads (8 waves), grid 256, grid-stride over 782 tiles of 128 rows.
// ZERO barriers in the row loop. __launch_bounds__(512, 2): LDS already
// limits to 1 block/CU (= 2 waves/EU) -> give the allocator the full 256
// VGPR budget; (512) default capped at 128 and spilled ~60 regs/thread,
// which was 500 MB of scratch HBM traffic (round-9 lesson).
// ---------------------------------------------------------------------------
__global__ __launch_bounds__(512, 2) void mlp_kernel(
    const unsigned short* __restrict__ updb,   // [N_PAD][256] bf16
    const unsigned short* __restrict__ w1b,    // [256][256] bf16
    const float* __restrict__ mlp_b,           // [256]
    unsigned short* __restrict__ hiddenb)      // [N_PAD][256] bf16 (phys perm)
{
    __shared__ __align__(16) char lds[131072];  // 128 units x 1024 B

    const int tid = threadIdx.x;
    const int w  = tid >> 6;
    const int l  = tid & 63;
    const int lr = l & 15;
    const int lg = l >> 4;

    // stage W1: wave w stages kt=w, nf=0..15
    #pragma unroll
    for (int i = 0; i < 16; ++i)
        GLOAD16(w1b + (size_t)(i * 16 + lr) * 256 + w * 32 + lg * 8,
                lds + (w * 16 + i) * 1024);

    float b1v[16];
    #pragma unroll
    for (int cf = 0; cf < 16; ++cf) b1v[cf] = mlp_b[cf * 16 + lr];

    __syncthreads();

    int tile = blockIdx.x;
    short8 af[8];
    if (tile < NT_TILES) {
        const unsigned short* p = updb + (size_t)(tile * 128 + w * 16 + lr) * 256 + lg * 8;
        #pragma unroll
        for (int kt = 0; kt < 8; ++kt)
            af[kt] = *reinterpret_cast<const short8*>(p + kt * 32);
    }

    for (; tile < NT_TILES; tile += 256) {
        // prefetch next tile's A while this tile's MFMA runs
        short8 afn[8];
        int tn = tile + 256;
        if (tn < NT_TILES) {
            const unsigned short* p = updb + (size_t)(tn * 128 + w * 16 + lr) * 256 + lg * 8;
            #pragma unroll
            for (int kt = 0; kt < 8; ++kt)
                afn[kt] = *reinterpret_cast<const short8*>(p + kt * 32);
        }

        floatx4 acc[16];
        #pragma unroll
        for (int i = 0; i < 16; ++i) acc[i] = (floatx4){0.f, 0.f, 0.f, 0.f};

        #pragma unroll
        for (int kt = 0; kt < 8; ++kt) {
            #pragma unroll
            for (int nf = 0; nf < 16; ++nf) {
                short8 bf = *reinterpret_cast<const short8*>(
                    lds + (kt * 16 + nf) * 1024 + l * 16);
                acc[nf] = __builtin_amdgcn_mfma_f32_16x16x32_bf16(af[kt], bf, acc[nf], 0, 0, 0);
            }
        }

        // epilogue: relu+bias, pack; lane (lg,lr): row r0+lg*4+q, 32B at lr*32
        const int r0 = tile * 128 + w * 16;
        #pragma unroll
        for (int q = 0; q < 4; ++q) {
            int row = r0 + lg * 4 + q;
            unsigned u_[8];
            #pragma unroll
            for (int j = 0; j < 8; ++j) {
                float v0 = fmaxf(acc[2 * j][q]     + b1v[2 * j],     0.f);
                float v1 = fmaxf(acc[2 * j + 1][q] + b1v[2 * j + 1], 0.f);
                u_[j] = pack2(v0, v1);
            }
            uint4* d = reinterpret_cast<uint4*>(
                (char*)hiddenb + (size_t)row * 512 + lr * 32);
            d[0] = make_uint4(u_[0], u_[1], u_[2], u_[3]);
            d[1] = make_uint4(u_[4], u_[5], u_[6], u_[7]);
        }

        #pragma unroll
        for (int kt = 0; kt < 8; ++kt) af[kt] = afn[kt];
    }
}

// ---------------------------------------------------------------------------
// Kernel B: GRU. w_ih (permuted, 96 KB) + w_hh (24 KB) stationary in LDS.
// Same __launch_bounds__(512, 2) fix: live set ~170 VGPRs.
// ---------------------------------------------------------------------------
__global__ __launch_bounds__(512, 2) void gru_kernel(
    const unsigned short* __restrict__ hiddenb, // [N_PAD][256] bf16 (phys)
    const unsigned short* __restrict__ xb,      // [N_PAD][64] bf16
    const unsigned short* __restrict__ wihp,    // [192][256] bf16, permuted
    const unsigned short* __restrict__ whhb,    // [192][64]  bf16
    const float* __restrict__ b_ih,             // [192]
    const float* __restrict__ b_hh,             // [192]
    const float* __restrict__ x,                // [N][64] f32
    float* __restrict__ out)                    // [N][64] f32
{
    __shared__ __align__(16) char lds[122880];  // 96 gi units + 24 gh units

    const int tid = threadIdx.x;
    const int w  = tid >> 6;
    const int l  = tid & 63;
    const int lr = l & 15;
    const int lg = l >> 4;

    // stage: 120 units, wave w stages u = w*15 .. w*15+14
    #pragma unroll
    for (int i = 0; i < 15; ++i) {
        int u = w * 15 + i;
        if (u < 96) {
            int kt = u / 12, nf = u % 12;
            GLOAD16(wihp + (size_t)(nf * 16 + lr) * 256 + kt * 32 + lg * 8,
                    lds + u * 1024);
        } else {
            int v = u - 96;
            int kt = v / 12, nf = v % 12;
            GLOAD16(whhb + (size_t)(nf * 16 + lr) * 64 + kt * 32 + lg * 8,
                    lds + u * 1024);
        }
    }

    // hoist biases: c = nf*16 + lr
    float bir[4], biz[4], bin[4], bhr[4], bhz[4], bhn[4];
    #pragma unroll
    for (int nf = 0; nf < 4; ++nf) {
        int c = nf * 16 + lr;
        bir[nf] = b_ih[c];       bhr[nf] = b_hh[c];
        biz[nf] = b_ih[64 + c];  bhz[nf] = b_hh[64 + c];
        bin[nf] = b_ih[128 + c]; bhn[nf] = b_hh[128 + c];
    }

    __syncthreads();

    for (int tile = blockIdx.x; tile < NT_TILES; tile += 256) {
        const int r0 = tile * 128 + w * 16;

        short8 afi[8];
        {
            const unsigned short* p = hiddenb + (size_t)(r0 + lr) * 256 + lg * 8;
            #pragma unroll
            for (int kt = 0; kt < 8; ++kt)
                afi[kt] = *reinterpret_cast<const short8*>(p + kt * 32);
        }
        short8 afh[2];
        {
            const unsigned short* p = xb + (size_t)(r0 + lr) * 64 + lg * 8;
            afh[0] = *reinterpret_cast<const short8*>(p);
            afh[1] = *reinterpret_cast<const short8*>(p + 32);
        }

        floatx4 ai[12], ah[12];
        #pragma unroll
        for (int i = 0; i < 12; ++i) {
            ai[i] = (floatx4){0.f, 0.f, 0.f, 0.f};
            ah[i] = (floatx4){0.f, 0.f, 0.f, 0.f};
        }

        #pragma unroll
        for (int kt = 0; kt < 8; ++kt) {
            #pragma unroll
            for (int nf = 0; nf < 12; ++nf) {
                short8 bf = *reinterpret_cast<const short8*>(
                    lds + (kt * 12 + nf) * 1024 + l * 16);
                ai[nf] = __builtin_amdgcn_mfma_f32_16x16x32_bf16(afi[kt], bf, ai[nf], 0, 0, 0);
            }
        }
        #pragma unroll
        for (int kt = 0; kt < 2; ++kt) {
            #pragma unroll
            for (int nf = 0; nf < 12; ++nf) {
                short8 bf = *reinterpret_cast<const short8*>(
                    lds + (96 + kt * 12 + nf) * 1024 + l * 16);
                ah[nf] = __builtin_amdgcn_mfma_f32_16x16x32_bf16(afh[kt], bf, ah[nf], 0, 0, 0);
            }
        }

        #pragma unroll
        for (int nf = 0; nf < 4; ++nf) {
            int c = nf * 16 + lr;
            #pragma unroll
            for (int q = 0; q < 4; ++q) {
                int row = r0 + lg * 4 + q;
                if (row < N_NODES) {
                    float ir = ai[nf    ][q] + bir[nf];
                    float iz = ai[nf + 4][q] + biz[nf];
                    float in_= ai[nf + 8][q] + bin[nf];
                    float hr = ah[nf    ][q] + bhr[nf];
                    float hz = ah[nf + 4][q] + bhz[nf];
                    float hn = ah[nf + 8][q] + bhn[nf];
                    float r = 1.0f / (1.0f + __expf(-(ir + hr)));
                    float z = 1.0f / (1.0f + __expf(-(iz + hz)));
                    float a = in_ + r * hn;
                    a = fminf(fmaxf(a, -30.f), 30.f);
                    float e2 = __expf(2.0f * a);
                    float n = (e2 - 1.0f) / (e2 + 1.0f);
                    float xv = x[(size_t)row * 64 + c];
                    out[(size_t)row * 64 + c] = (1.0f - z) * n + z * xv;
                }
            }
        }
    }
}

// ---------------------------------------------------------------------------
extern "C" void kernel_launch(void* const* d_in, const int* in_sizes, int n_in,
                              void* d_out, int out_size, void* d_ws, size_t ws_size,
                              hipStream_t stream) {
    const float* node_feature = (const float*)d_in[0];
    const int*   edge_index   = (const int*)d_in[1];
    const int*   edge_type    = (const int*)d_in[2];
    const float* edge_weight  = (const float*)d_in[3];
    const float* mlp_W        = (const float*)d_in[4];
    const float* mlp_b        = (const float*)d_in[5];
    const float* w_ih         = (const float*)d_in[6];
    const float* w_hh         = (const float*)d_in[7];
    const float* b_ih         = (const float*)d_in[8];
    const float* b_hh         = (const float*)d_in[9];
    float* out = (float*)d_out;

    // workspace layout
    unsigned short* updb    = (unsigned short*)d_ws;            // [N_PAD][256]
    unsigned short* xb      = updb + (size_t)N_PAD * 256;       // [N_PAD][64]
    unsigned short* hiddenb = xb + (size_t)N_PAD * 64;          // [N_PAD][256]
    unsigned short* w1b     = hiddenb + (size_t)N_PAD * 256;    // [256][256]
    unsigned short* wihp    = w1b + 65536;                      // [192][256]
    unsigned short* whhb    = wihp + 49152;                     // [192][64]
    int* counts   = (int*)(whhb + 12288);                       // [NSEG]
    int* offsets  = counts + 400064;                            // [NSEG+1]
    int* partials = offsets + 400064;                           // [512]
    int* cursor   = partials + 512;                             // [NSEG]
    int2* recs    = (int2*)(cursor + 400064);                   // [E]

    const int NB1 = (NSEG + 1023) / 1024;

    hipMemsetAsync(counts, 0, (size_t)NSEG * sizeof(int), stream);

    conv_x_kernel<<<(N_PAD * 16 + 255) / 256, 256, 0, stream>>>(node_feature, xb);
    conv_w_kernel<<<(126976 + 255) / 256, 256, 0, stream>>>(
        mlp_W, w_ih, w_hh, w1b, wihp, whhb);

    hist_kernel<<<(N_EDGES + 255) / 256, 256, 0, stream>>>(
        edge_index, edge_type, counts);
    scan1_kernel<<<NB1, 256, 0, stream>>>(counts, offsets, partials);
    scan2_kernel<<<1, 512, 0, stream>>>(partials, NB1);
    scan3_kernel<<<(NSEG + 255) / 256, 256, 0, stream>>>(offsets, partials, cursor);
    place_kernel<<<(N_EDGES + 255) / 256, 256, 0, stream>>>(
        edge_index, edge_type, edge_weight, cursor, recs);
    gather_kernel<<<(NSEG * 16 + 255) / 256, 256, 0, stream>>>(
        xb, offsets, recs, (unsigned*)updb);

    mlp_kernel<<<256, 512, 0, stream>>>(updb, w1b, mlp_b, hiddenb);
    gru_kernel<<<256, 512, 0, stream>>>(
        hiddenb, xb, wihp, whhb, b_ih, b_hh, node_feature, out);
}

// Round 11
// 711.519 us; speedup vs baseline: 1.1119x; 1.1119x over previous
//
#include <hip/hip_runtime.h>
#include <hip/hip_bf16.h>
#include <math.h>

// Problem constants (fixed by the reference)
#define N_NODES   100000
#define N_PAD     100096   // multiple of 128 (782 row-tiles), safe OOB rows
#define NT_TILES  782      // N_PAD / 128
#define N_EDGES   1000000
#define D_IN      64
#define T_ET      4
#define H_DIM     256
#define TD        256      // T_ET * D_IN
#define NSEG      400000   // N_NODES * T_ET

typedef __attribute__((ext_vector_type(8))) short short8;   // 8 bf16 (4 VGPRs)
typedef __attribute__((ext_vector_type(4))) float floatx4;  // MFMA C/D

__device__ __forceinline__ unsigned short f2b(float f) {
    __hip_bfloat16 h = __float2bfloat16(f);
    return *reinterpret_cast<unsigned short*>(&h);
}
__device__ __forceinline__ unsigned pack2(float a, float b) {
    return (unsigned)f2b(a) | ((unsigned)f2b(b) << 16);
}

// global->LDS DMA: 16 B per lane, LDS dst = wave-uniform base + lane*16
#define GLOAD16(gsrc, ldst)                                                  \
    __builtin_amdgcn_global_load_lds(                                        \
        (const __attribute__((address_space(1))) unsigned int*)(gsrc),       \
        (__attribute__((address_space(3))) unsigned int*)(ldst), 16, 0, 0)

// ---------------------------------------------------------------------------
// CSR build (unchanged): histogram -> scan -> place
// ---------------------------------------------------------------------------
__global__ __launch_bounds__(256) void hist_kernel(
    const int* __restrict__ edge_index, const int* __restrict__ edge_type,
    int* __restrict__ counts)
{
    int e = blockIdx.x * 256 + threadIdx.x;
    if (e >= N_EDGES) return;
    int dst = edge_index[N_EDGES + e];
    int ty  = edge_type[e];
    atomicAdd(&counts[dst * T_ET + ty], 1);
}

__global__ __launch_bounds__(256) void scan1_kernel(
    const int* __restrict__ counts, int* __restrict__ offsets,
    int* __restrict__ partials)
{
    __shared__ int tsum[256];
    const int tid = threadIdx.x;
    const int base = blockIdx.x * 1024 + tid * 4;
    int v[4]; int s = 0;
    #pragma unroll
    for (int i = 0; i < 4; ++i) {
        v[i] = (base + i < NSEG) ? counts[base + i] : 0;
        s += v[i];
    }
    tsum[tid] = s;
    __syncthreads();
    #pragma unroll
    for (int off = 1; off < 256; off <<= 1) {
        int t = (tid >= off) ? tsum[tid - off] : 0;
        __syncthreads();
        tsum[tid] += t;
        __syncthreads();
    }
    int run = tsum[tid] - s;
    #pragma unroll
    for (int i = 0; i < 4; ++i) {
        if (base + i < NSEG) offsets[base + i] = run;
        run += v[i];
    }
    if (tid == 255) partials[blockIdx.x] = tsum[255];
}

__global__ __launch_bounds__(512) void scan2_kernel(int* __restrict__ partials, int nb)
{
    __shared__ int sh[512];
    const int tid = threadIdx.x;
    int v = (tid < nb) ? partials[tid] : 0;
    sh[tid] = v;
    __syncthreads();
    #pragma unroll
    for (int off = 1; off < 512; off <<= 1) {
        int t = (tid >= off) ? sh[tid - off] : 0;
        __syncthreads();
        sh[tid] += t;
        __syncthreads();
    }
    if (tid < nb) partials[tid] = sh[tid] - v;
}

__global__ __launch_bounds__(256) void scan3_kernel(
    int* __restrict__ offsets, const int* __restrict__ partials,
    int* __restrict__ cursor)
{
    int i = blockIdx.x * 256 + threadIdx.x;
    if (i < NSEG) {
        int o = offsets[i] + partials[i >> 10];
        offsets[i] = o;
        cursor[i]  = o;
    }
    if (i == 0) offsets[NSEG] = N_EDGES;
}

__global__ __launch_bounds__(256) void place_kernel(
    const int* __restrict__ edge_index, const int* __restrict__ edge_type,
    const float* __restrict__ edge_w, int* __restrict__ cursor,
    int2* __restrict__ recs)
{
    int e = blockIdx.x * 256 + threadIdx.x;
    if (e >= N_EDGES) return;
    int src = edge_index[e];
    int dst = edge_index[N_EDGES + e];
    int ty  = edge_type[e];
    int seg = dst * T_ET + ty;
    int pos = atomicAdd(&cursor[seg], 1);
    recs[pos] = make_int2(src, __float_as_int(edge_w[e]));
}

// gather: 16 threads per segment; reads bf16 xb, accumulates f32, writes bf16
__global__ __launch_bounds__(256) void gather_kernel(
    const unsigned short* __restrict__ xb, const int* __restrict__ offsets,
    const int2* __restrict__ recs, unsigned* __restrict__ updb_u32)
{
    int gid = blockIdx.x * 256 + threadIdx.x;
    int seg = gid >> 4;
    int t   = gid & 15;
    if (seg >= NSEG) return;
    int start = offsets[seg];
    int end   = offsets[seg + 1];
    float a0 = 0.f, a1 = 0.f, a2 = 0.f, a3 = 0.f;
    for (int p = start; p < end; ++p) {
        int2 r = recs[p];
        float w = __int_as_float(r.y);
        uint2 xv = reinterpret_cast<const uint2*>(xb)[r.x * 16 + t];
        a0 += w * __uint_as_float(xv.x << 16);
        a1 += w * __uint_as_float(xv.x & 0xffff0000u);
        a2 += w * __uint_as_float(xv.y << 16);
        a3 += w * __uint_as_float(xv.y & 0xffff0000u);
    }
    uint2 o;
    o.x = pack2(a0, a1);
    o.y = pack2(a2, a3);
    reinterpret_cast<uint2*>(updb_u32)[seg * 16 + t] = o;
}

// ---------------------------------------------------------------------------
// prep: f32 -> bf16. w_ih permuted with the hidden physical layout:
//   phys p holds logical col c(p) = (p&15)*16 + (p>>4)
// ---------------------------------------------------------------------------
__global__ __launch_bounds__(256) void conv_x_kernel(
    const float* __restrict__ x, unsigned short* __restrict__ xb)
{
    int i = blockIdx.x * 256 + threadIdx.x;
    if (i >= N_PAD * 16) return;
    int row = i >> 4;
    int srow = row < N_NODES ? row : N_NODES - 1;
    float4 v = reinterpret_cast<const float4*>(x)[srow * 16 + (i & 15)];
    uint2 o;
    o.x = pack2(v.x, v.y);
    o.y = pack2(v.z, v.w);
    reinterpret_cast<uint2*>(xb)[i] = o;
}

__global__ __launch_bounds__(256) void conv_w_kernel(
    const float* __restrict__ w1, const float* __restrict__ wih,
    const float* __restrict__ whh,
    unsigned short* __restrict__ w1b, unsigned short* __restrict__ wihp,
    unsigned short* __restrict__ whhb)
{
    int i = blockIdx.x * 256 + threadIdx.x;
    if (i < 65536) { w1b[i] = f2b(w1[i]); return; }
    i -= 65536;
    if (i < 49152) {
        int n = i >> 8, p = i & 255;
        int k = (p & 15) * 16 + (p >> 4);
        wihp[i] = f2b(wih[n * 256 + k]);
        return;
    }
    i -= 49152;
    if (i < 12288) whhb[i] = f2b(whh[i]);
}

// ---------------------------------------------------------------------------
// Kernel A: hidden = relu(upd @ W1^T + b1), W1-stationary in LDS (128 KB).
// Round-11 restructure: OUTPUT-COLUMN SPLIT to kill register spills.
// Per tile: load af[8] once (stays live), then two passes of acc[8]
// (cols 0..127, then 128..255). Peak live ~90 VGPR < 128 -> no scratch.
// (Round 9/10: acc[16]+af[8]+afn[8] > 128 VGPR cap -> ~500 MB scratch
// traffic, 6x HBM amplification, 270 us. Prefetch dropped deliberately.)
// ---------------------------------------------------------------------------
__global__ __launch_bounds__(512, 2) void mlp_kernel(
    const unsigned short* __restrict__ updb,   // [N_PAD][256] bf16
    const unsigned short* __restrict__ w1b,    // [256][256] bf16
    const float* __restrict__ mlp_b,           // [256]
    unsigned short* __restrict__ hiddenb)      // [N_PAD][256] bf16 (phys perm)
{
    __shared__ __align__(16) char lds[131072];  // 128 units x 1024 B

    const int tid = threadIdx.x;
    const int w  = tid >> 6;
    const int l  = tid & 63;
    const int lr = l & 15;
    const int lg = l >> 4;

    // stage W1: wave w stages kt=w, nf=0..15
    #pragma unroll
    for (int i = 0; i < 16; ++i)
        GLOAD16(w1b + (size_t)(i * 16 + lr) * 256 + w * 32 + lg * 8,
                lds + (w * 16 + i) * 1024);

    __syncthreads();

    for (int tile = blockIdx.x; tile < NT_TILES; tile += 256) {
        const int r0 = tile * 128 + w * 16;

        // A fragments: loaded once, live across both passes
        short8 af[8];
        {
            const unsigned short* p = updb + (size_t)(r0 + lr) * 256 + lg * 8;
            #pragma unroll
            for (int kt = 0; kt < 8; ++kt)
                af[kt] = *reinterpret_cast<const short8*>(p + kt * 32);
        }

        #pragma unroll
        for (int pass = 0; pass < 2; ++pass) {
            floatx4 acc[8];
            #pragma unroll
            for (int i = 0; i < 8; ++i) acc[i] = (floatx4){0.f, 0.f, 0.f, 0.f};

            #pragma unroll
            for (int kt = 0; kt < 8; ++kt) {
                #pragma unroll
                for (int nf = 0; nf < 8; ++nf) {
                    short8 bf = *reinterpret_cast<const short8*>(
                        lds + (kt * 16 + pass * 8 + nf) * 1024 + l * 16);
                    acc[nf] = __builtin_amdgcn_mfma_f32_16x16x32_bf16(af[kt], bf, acc[nf], 0, 0, 0);
                }
            }

            // epilogue: relu+bias; lane (lg,lr), row r0+lg*4+q,
            // 16 B at row*512 + lr*32 + pass*16 (phys p = lr*16 + pass*8 + j)
            #pragma unroll
            for (int q = 0; q < 4; ++q) {
                int row = r0 + lg * 4 + q;
                unsigned u_[4];
                #pragma unroll
                for (int j = 0; j < 4; ++j) {
                    int cf0 = pass * 8 + 2 * j;
                    float v0 = fmaxf(acc[2 * j][q]     + mlp_b[cf0 * 16 + lr],       0.f);
                    float v1 = fmaxf(acc[2 * j + 1][q] + mlp_b[(cf0 + 1) * 16 + lr], 0.f);
                    u_[j] = pack2(v0, v1);
                }
                *reinterpret_cast<uint4*>(
                    (char*)hiddenb + (size_t)row * 512 + lr * 32 + pass * 16) =
                    make_uint4(u_[0], u_[1], u_[2], u_[3]);
            }
        }
    }
}

// ---------------------------------------------------------------------------
// Kernel B: GRU. w_ih (permuted, 96 KB) + w_hh (24 KB) stationary in LDS.
// Same column-split: afi[8]+afh[2] live across two passes of 6 fragments
// (pass p covers nf in {2p, 2p+1} x 3 gates). Peak live ~110 VGPR.
// ---------------------------------------------------------------------------
__global__ __launch_bounds__(512, 2) void gru_kernel(
    const unsigned short* __restrict__ hiddenb, // [N_PAD][256] bf16 (phys)
    const unsigned short* __restrict__ xb,      // [N_PAD][64] bf16
    const unsigned short* __restrict__ wihp,    // [192][256] bf16, permuted
    const unsigned short* __restrict__ whhb,    // [192][64]  bf16
    const float* __restrict__ b_ih,             // [192]
    const float* __restrict__ b_hh,             // [192]
    const float* __restrict__ x,                // [N][64] f32
    float* __restrict__ out)                    // [N][64] f32
{
    __shared__ __align__(16) char lds[122880];  // 96 gi units + 24 gh units

    const int tid = threadIdx.x;
    const int w  = tid >> 6;
    const int l  = tid & 63;
    const int lr = l & 15;
    const int lg = l >> 4;

    // stage: 120 units, wave w stages u = w*15 .. w*15+14
    #pragma unroll
    for (int i = 0; i < 15; ++i) {
        int u = w * 15 + i;
        if (u < 96) {
            int kt = u / 12, nf = u % 12;
            GLOAD16(wihp + (size_t)(nf * 16 + lr) * 256 + kt * 32 + lg * 8,
                    lds + u * 1024);
        } else {
            int v = u - 96;
            int kt = v / 12, nf = v % 12;
            GLOAD16(whhb + (size_t)(nf * 16 + lr) * 64 + kt * 32 + lg * 8,
                    lds + u * 1024);
        }
    }

    __syncthreads();

    for (int tile = blockIdx.x; tile < NT_TILES; tile += 256) {
        const int r0 = tile * 128 + w * 16;

        short8 afi[8];
        {
            const unsigned short* p = hiddenb + (size_t)(r0 + lr) * 256 + lg * 8;
            #pragma unroll
            for (int kt = 0; kt < 8; ++kt)
                afi[kt] = *reinterpret_cast<const short8*>(p + kt * 32);
        }
        short8 afh[2];
        {
            const unsigned short* p = xb + (size_t)(r0 + lr) * 64 + lg * 8;
            afh[0] = *reinterpret_cast<const short8*>(p);
            afh[1] = *reinterpret_cast<const short8*>(p + 32);
        }

        #pragma unroll
        for (int pass = 0; pass < 2; ++pass) {
            floatx4 ai[6], ah[6];
            #pragma unroll
            for (int i = 0; i < 6; ++i) {
                ai[i] = (floatx4){0.f, 0.f, 0.f, 0.f};
                ah[i] = (floatx4){0.f, 0.f, 0.f, 0.f};
            }

            // fragment ids: gate g, local n (0..1) -> global nf = g*4 + pass*2 + n
            #pragma unroll
            for (int kt = 0; kt < 8; ++kt) {
                #pragma unroll
                for (int g = 0; g < 3; ++g) {
                    #pragma unroll
                    for (int n = 0; n < 2; ++n) {
                        int frag = g * 4 + pass * 2 + n;
                        short8 bf = *reinterpret_cast<const short8*>(
                            lds + (kt * 12 + frag) * 1024 + l * 16);
                        ai[g * 2 + n] = __builtin_amdgcn_mfma_f32_16x16x32_bf16(
                            afi[kt], bf, ai[g * 2 + n], 0, 0, 0);
                    }
                }
            }
            #pragma unroll
            for (int kt = 0; kt < 2; ++kt) {
                #pragma unroll
                for (int g = 0; g < 3; ++g) {
                    #pragma unroll
                    for (int n = 0; n < 2; ++n) {
                        int frag = g * 4 + pass * 2 + n;
                        short8 bf = *reinterpret_cast<const short8*>(
                            lds + (96 + kt * 12 + frag) * 1024 + l * 16);
                        ah[g * 2 + n] = __builtin_amdgcn_mfma_f32_16x16x32_bf16(
                            afh[kt], bf, ah[g * 2 + n], 0, 0, 0);
                    }
                }
            }

            // gates + output: col c = (pass*2 + n)*16 + lr
            #pragma unroll
            for (int n = 0; n < 2; ++n) {
                int c = (pass * 2 + n) * 16 + lr;
                float bir = b_ih[c],       bhr = b_hh[c];
                float biz = b_ih[64 + c],  bhz = b_hh[64 + c];
                float bin = b_ih[128 + c], bhn = b_hh[128 + c];
                #pragma unroll
                for (int q = 0; q < 4; ++q) {
                    int row = r0 + lg * 4 + q;
                    if (row < N_NODES) {
                        float ir = ai[0 * 2 + n][q] + bir;
                        float iz = ai[1 * 2 + n][q] + biz;
                        float in_= ai[2 * 2 + n][q] + bin;
                        float hr = ah[0 * 2 + n][q] + bhr;
                        float hz = ah[1 * 2 + n][q] + bhz;
                        float hn = ah[2 * 2 + n][q] + bhn;
                        float r = 1.0f / (1.0f + __expf(-(ir + hr)));
                        float z = 1.0f / (1.0f + __expf(-(iz + hz)));
                        float a = in_ + r * hn;
                        a = fminf(fmaxf(a, -30.f), 30.f);
                        float e2 = __expf(2.0f * a);
                        float nn = (e2 - 1.0f) / (e2 + 1.0f);
                        float xv = x[(size_t)row * 64 + c];
                        out[(size_t)row * 64 + c] = (1.0f - z) * nn + z * xv;
                    }
                }
            }
        }
    }
}

// ---------------------------------------------------------------------------
extern "C" void kernel_launch(void* const* d_in, const int* in_sizes, int n_in,
                              void* d_out, int out_size, void* d_ws, size_t ws_size,
                              hipStream_t stream) {
    const float* node_feature = (const float*)d_in[0];
    const int*   edge_index   = (const int*)d_in[1];
    const int*   edge_type    = (const int*)d_in[2];
    const float* edge_weight  = (const float*)d_in[3];
    const float* mlp_W        = (const float*)d_in[4];
    const float* mlp_b        = (const float*)d_in[5];
    const float* w_ih         = (const float*)d_in[6];
    const float* w_hh         = (const float*)d_in[7];
    const float* b_ih         = (const float*)d_in[8];
    const float* b_hh         = (const float*)d_in[9];
    float* out = (float*)d_out;

    // workspace layout
    unsigned short* updb    = (unsigned short*)d_ws;            // [N_PAD][256]
    unsigned short* xb      = updb + (size_t)N_PAD * 256;       // [N_PAD][64]
    unsigned short* hiddenb = xb + (size_t)N_PAD * 64;          // [N_PAD][256]
    unsigned short* w1b     = hiddenb + (size_t)N_PAD * 256;    // [256][256]
    unsigned short* wihp    = w1b + 65536;                      // [192][256]
    unsigned short* whhb    = wihp + 49152;                     // [192][64]
    int* counts   = (int*)(whhb + 12288);                       // [NSEG]
    int* offsets  = counts + 400064;                            // [NSEG+1]
    int* partials = offsets + 400064;                           // [512]
    int* cursor   = partials + 512;                             // [NSEG]
    int2* recs    = (int2*)(cursor + 400064);                   // [E]

    const int NB1 = (NSEG + 1023) / 1024;

    hipMemsetAsync(counts, 0, (size_t)NSEG * sizeof(int), stream);

    conv_x_kernel<<<(N_PAD * 16 + 255) / 256, 256, 0, stream>>>(node_feature, xb);
    conv_w_kernel<<<(126976 + 255) / 256, 256, 0, stream>>>(
        mlp_W, w_ih, w_hh, w1b, wihp, whhb);

    hist_kernel<<<(N_EDGES + 255) / 256, 256, 0, stream>>>(
        edge_index, edge_type, counts);
    scan1_kernel<<<NB1, 256, 0, stream>>>(counts, offsets, partials);
    scan2_kernel<<<1, 512, 0, stream>>>(partials, NB1);
    scan3_kernel<<<(NSEG + 255) / 256, 256, 0, stream>>>(offsets, partials, cursor);
    place_kernel<<<(N_EDGES + 255) / 256, 256, 0, stream>>>(
        edge_index, edge_type, edge_weight, cursor, recs);
    gather_kernel<<<(NSEG * 16 + 255) / 256, 256, 0, stream>>>(
        xb, offsets, recs, (unsigned*)updb);

    mlp_kernel<<<256, 512, 0, stream>>>(updb, w1b, mlp_b, hiddenb);
    gru_kernel<<<256, 512, 0, stream>>>(
        hiddenb, xb, wihp, whhb, b_ih, b_hh, node_feature, out);
}